// Round 4
// baseline (2971.175 us; speedup 1.0000x reference)
//
#include <hip/hip_runtime.h>
#include <hip/hip_bf16.h>
#include <math.h>

typedef __bf16 bf16_t;
typedef __bf16 bf16x8 __attribute__((ext_vector_type(8)));
typedef float  f32x4 __attribute__((ext_vector_type(4)));
typedef float  f4    __attribute__((ext_vector_type(4)));
typedef unsigned long long u64x2 __attribute__((ext_vector_type(2)));

#define HS  512
#define BB  128
#define TT  40
#define VV  10000
#define VGGN 4096
#define SLOT ((size_t)65536)   // 128*512
#define NBLK 72

// ============================================================================
// Coherent (agent-scope, L3-point) accessors. These compile to sc-flagged
// global ops that bypass/write through the non-coherent per-XCD L2 — NO
// whole-L2 flush (round 3's __threadfence() wbl2/inv was 26.5 us/barrier).
// ============================================================================
__device__ __forceinline__ float cload(const float* p) {
  return __hip_atomic_load(p, __ATOMIC_RELAXED, __HIP_MEMORY_SCOPE_AGENT);
}
__device__ __forceinline__ void cstore(float* p, float v) {
  __hip_atomic_store(p, v, __ATOMIC_RELAXED, __HIP_MEMORY_SCOPE_AGENT);
}
__device__ __forceinline__ void cstore16(bf16_t* p, bf16_t v) {
  __hip_atomic_store((unsigned short*)p, __builtin_bit_cast(unsigned short, v),
                     __ATOMIC_RELAXED, __HIP_MEMORY_SCOPE_AGENT);
}
__device__ __forceinline__ unsigned long long cload64(const bf16_t* p) {
  return __hip_atomic_load((const unsigned long long*)p,
                           __ATOMIC_RELAXED, __HIP_MEMORY_SCOPE_AGENT);
}

// ============================================================================
// Fence-free grid barrier. Monotonic arrival counter (no reset -> no
// reset/arrive race); gen word polled. Ordering: __syncthreads() drains
// vmcnt(0) for every wave (compiler-emitted before s_barrier), so the arrive
// atomic is issued only after all of this block's stores ACKed at L3.
// Consumer loads issue after the poll's dependent branch (in-order wave).
// All cross-block data uses the coherent accessors above.
// ============================================================================
__device__ __forceinline__ void gbar(unsigned* cnt, unsigned* gen, unsigned bar_idx)
{
  __syncthreads();
  if (threadIdx.x == 0) {
    unsigned a = __hip_atomic_fetch_add(cnt, 1u, __ATOMIC_RELAXED,
                                        __HIP_MEMORY_SCOPE_AGENT);
    if (a == (bar_idx + 1u) * NBLK - 1u) {
      __hip_atomic_store(gen, bar_idx + 1u, __ATOMIC_RELAXED,
                         __HIP_MEMORY_SCOPE_AGENT);
    } else {
      while (__hip_atomic_load(gen, __ATOMIC_RELAXED,
                               __HIP_MEMORY_SCOPE_AGENT) <= bar_idx)
        __builtin_amdgcn_s_sleep(2);
    }
  }
  __syncthreads();
}

__global__ void zero_sync(unsigned* p) { p[0] = 0u; p[1] = 0u; }

// ============================================================================
// Batched MFMA GEMM: C[M,N] = A[M,512] @ Bt[N,512]^T (+bias), fp32 out.
// ============================================================================
__global__ __launch_bounds__(256) void gemm_bt(
    const bf16_t* __restrict__ A, const bf16_t* __restrict__ Bt,
    const float* __restrict__ bias, float* __restrict__ C,
    int Nvalid, int ldc, int permute_tb)
{
  const int bm = blockIdx.x * 128, bn = blockIdx.y * 128;
  const int tid = threadIdx.x;
  const int wave = tid >> 6, lane = tid & 63;
  const int wm = (wave >> 1) * 64, wn = (wave & 1) * 64;
  const int l15 = lane & 15, kg = lane >> 4;
  const bf16_t* Ap = A + (size_t)(bm + wm + l15) * 512 + kg * 8;
  const bf16_t* Bp = Bt + (size_t)(bn + wn + l15) * 512 + kg * 8;
  f32x4 acc[4][4];
#pragma unroll
  for (int i = 0; i < 4; ++i)
#pragma unroll
    for (int j = 0; j < 4; ++j)
#pragma unroll
      for (int e = 0; e < 4; ++e) acc[i][j][e] = 0.f;

  for (int kk = 0; kk < 512; kk += 32) {
    bf16x8 a[4], b[4];
#pragma unroll
    for (int i = 0; i < 4; ++i) a[i] = *(const bf16x8*)(Ap + (size_t)i * 16 * 512 + kk);
#pragma unroll
    for (int j = 0; j < 4; ++j) b[j] = *(const bf16x8*)(Bp + (size_t)j * 16 * 512 + kk);
#pragma unroll
    for (int i = 0; i < 4; ++i)
#pragma unroll
      for (int j = 0; j < 4; ++j)
        acc[i][j] = __builtin_amdgcn_mfma_f32_16x16x32_bf16(a[i], b[j], acc[i][j], 0, 0, 0);
  }

#pragma unroll
  for (int fm = 0; fm < 4; ++fm) {
#pragma unroll
    for (int fn = 0; fn < 4; ++fn) {
      int n = bn + wn + fn * 16 + l15;
      if (n >= Nvalid) continue;
      float bv = bias ? bias[n] : 0.f;
#pragma unroll
      for (int e = 0; e < 4; ++e) {
        int m = bm + wm + fm * 16 + kg * 4 + e;
        int orow = permute_tb ? ((m & 127) * TT + (m >> 7)) : m;
        C[(size_t)orow * ldc + n] = acc[fm][fn][e] + bv;
      }
    }
  }
}

// ============================================================================
// Persistent GRU recurrence (same role/stage structure as round 3).
//   blocks [ 0,16): RU layer0  64 rows of Btru0 [1024,512]   K=512
//   blocks [16,48): RU layer1  32 rows of Bt1ru [1024,1024]  K=1024
//   blocks [48,56): C  layer0  64 rows of Btc0  [512,512]    K=512
//   blocks [56,72): C  layer1  32 rows of Btc1  [512,1024]   K=1024
// hb0_seq[k]=bf16 H0[k] (k=0..40), hb1_seq[k]=bf16 H1[k] (k=0..40, slot0=init).
// Slotted (write-once) panels -> plain cached loads; in-place buffers
// (u0/u1/hs0/hs1/rh0/rh1) -> coherent accessors only.
// ============================================================================
struct PArgs {
  const bf16_t *Btru0, *Bt1ru, *Btc0, *Btc1;
  const float  *xg0, *bu, *br, *bc;
  bf16_t *hb0_seq, *hb1_seq, *rh0, *rh1;
  float  *hs0, *hs1, *u0, *u1;
  unsigned *sync;   // [0]=cnt, [1]=gen
};

template<int K, bool C0, bool C1>
__device__ __forceinline__ void tile_gemm(
    const bf16_t* __restrict__ A0, const bf16_t* __restrict__ A1,
    const bf16_t* Bs, int wave, int lane, f32x4 (&acc)[2][4])
{
  constexpr int NF = (K == 512) ? 4 : 2;
  const int l15 = lane & 15, kg = lane >> 4;
  const int mw = wave * 32;
#pragma unroll
  for (int i = 0; i < 2; ++i)
#pragma unroll
    for (int f = 0; f < 4; ++f)
#pragma unroll
      for (int e = 0; e < 4; ++e) acc[i][f][e] = 0.f;

#pragma unroll
  for (int kk = 0; kk < K; kk += 32) {
    const bf16_t* Asrc = (kk < 512) ? A0 : A1;
    const bool coh = (kk < 512) ? C0 : C1;   // folds: kk literal per unrolled iter
    const int kc = (kk < 512 ? kk : kk - 512) + kg * 8;
    bf16x8 a[2];
#pragma unroll
    for (int i = 0; i < 2; ++i) {
      const bf16_t* ap = Asrc + (size_t)(mw + i * 16 + l15) * 512 + kc;
      if (coh) {
        u64x2 t;
        t.x = cload64(ap);
        t.y = cload64(ap + 4);
        a[i] = __builtin_bit_cast(bf16x8, t);
      } else {
        a[i] = *(const bf16x8*)ap;
      }
    }
    bf16x8 b[NF];
#pragma unroll
    for (int f = 0; f < NF; ++f) {
      int row = f * 16 + l15;
      int byteoff = row * (2 * K) + ((2 * kk + 16 * kg) ^ ((row & 7) << 4));
      b[f] = *(const bf16x8*)((const char*)Bs + byteoff);
    }
#pragma unroll
    for (int i = 0; i < 2; ++i)
#pragma unroll
      for (int f = 0; f < NF; ++f)
        acc[i][f] = __builtin_amdgcn_mfma_f32_16x16x32_bf16(a[i], b[f], acc[i][f], 0, 0, 0);
  }
}

__global__ __launch_bounds__(256) void gru_persist(PArgs P)
{
  const int bid = blockIdx.x, tid = threadIdx.x;
  const int wave = tid >> 6, lane = tid & 63;
  const int l15 = lane & 15, kg = lane >> 4;
  const int mw = wave * 32;
  unsigned* cnt = P.sync;
  unsigned* gen = P.sync + 1;

  int role, q;
  if (bid < 16)      { role = 0; q = bid; }
  else if (bid < 48) { role = 1; q = bid - 16; }
  else if (bid < 56) { role = 2; q = bid - 48; }
  else               { role = 3; q = bid - 56; }
  const int K  = (role == 0 || role == 2) ? 512 : 1024;
  const int NT = (K == 512) ? 64 : 32;
  const int tileBase = q * NT;

  const bf16_t* Wsrc =
      role == 0 ? P.Btru0 + (size_t)tileBase * 512 :
      role == 1 ? P.Bt1ru + (size_t)tileBase * 1024 :
      role == 2 ? P.Btc0  + (size_t)tileBase * 512 :
                  P.Btc1  + (size_t)tileBase * 1024;

  // ---- stage weight tile into LDS once, swizzled ----
  __shared__ bf16_t Bs[32768];   // 64 KB
  {
    const int rsh = (K == 512) ? 10 : 11;
    const int rmask = 2 * K - 1;
#pragma unroll
    for (int it = 0; it < 16; ++it) {
      int ofs = (it * 256 + tid) * 16;
      int row = ofs >> rsh, cb = ofs & rmask;
      *(f4*)((char*)Bs + row * 2 * K + (cb ^ ((row & 7) << 4))) =
          *(const f4*)((const char*)Wsrc + ofs);
    }
  }
  __syncthreads();

  for (int s = 0; s <= 40; ++s) {
    // ---------------- phase RU ----------------
    if (role == 0 && s < 40) {
      f32x4 acc[2][4];
      const bf16_t* A0 = P.hb0_seq + (size_t)s * SLOT;
      tile_gemm<512, false, false>(A0, A0, Bs, wave, lane, acc);
      const float* xg = P.xg0 + (size_t)s * 128 * 1536;
#pragma unroll
      for (int i = 0; i < 2; ++i)
#pragma unroll
        for (int f = 0; f < 4; ++f)
#pragma unroll
          for (int e = 0; e < 4; ++e) {
            int m = mw + i * 16 + kg * 4 + e;
            int np = tileBase + f * 16 + l15;
            float pre = acc[i][f][e] + xg[(size_t)m * 1536 + np];
            float sg = 1.f / (1.f + expf(-pre));
            if (np < 512) {
              cstore(&P.u0[m * 512 + np], sg);
            } else {
              int n = np - 512;
              float h = cload(&P.hs0[m * 512 + n]);
              cstore16(&P.rh0[m * 512 + n], (bf16_t)(sg * h));
            }
          }
    } else if (role == 1 && s >= 1) {
      f32x4 acc[2][4];
      tile_gemm<1024, false, false>(P.hb0_seq + (size_t)s * SLOT,
                                    P.hb1_seq + (size_t)(s - 1) * SLOT,
                                    Bs, wave, lane, acc);
#pragma unroll
      for (int i = 0; i < 2; ++i)
#pragma unroll
        for (int f = 0; f < 2; ++f)
#pragma unroll
          for (int e = 0; e < 4; ++e) {
            int m = mw + i * 16 + kg * 4 + e;
            int np = tileBase + f * 16 + l15;
            float bias = (np < 512) ? P.bu[512 + np] : P.br[np];
            float pre = acc[i][f][e] + bias;
            float sg = 1.f / (1.f + expf(-pre));
            if (np < 512) {
              cstore(&P.u1[m * 512 + np], sg);
            } else {
              int n = np - 512;
              float h = cload(&P.hs1[m * 512 + n]);
              cstore16(&P.rh1[m * 512 + n], (bf16_t)(sg * h));
            }
          }
    }
    gbar(cnt, gen, 2 * s);
    // ---------------- phase C ----------------
    if (role == 2 && s < 40) {
      f32x4 acc[2][4];
      tile_gemm<512, true, true>(P.rh0, P.rh0, Bs, wave, lane, acc);
      const float* xg = P.xg0 + (size_t)s * 128 * 1536;
#pragma unroll
      for (int i = 0; i < 2; ++i)
#pragma unroll
        for (int f = 0; f < 4; ++f)
#pragma unroll
          for (int e = 0; e < 4; ++e) {
            int m = mw + i * 16 + kg * 4 + e;
            int n = tileBase + f * 16 + l15;
            float c = tanhf(acc[i][f][e] + xg[(size_t)m * 1536 + 1024 + n]);
            float u = cload(&P.u0[m * 512 + n]);
            float h = cload(&P.hs0[m * 512 + n]);
            float hn = u * h + (1.f - u) * c;
            cstore(&P.hs0[m * 512 + n], hn);
            cstore16(&P.hb0_seq[(size_t)(s + 1) * SLOT + m * 512 + n], (bf16_t)hn);
          }
    } else if (role == 3 && s >= 1) {
      f32x4 acc[2][4];
      tile_gemm<1024, false, true>(P.hb0_seq + (size_t)s * SLOT, P.rh1,
                                   Bs, wave, lane, acc);
#pragma unroll
      for (int i = 0; i < 2; ++i)
#pragma unroll
        for (int f = 0; f < 2; ++f)
#pragma unroll
          for (int e = 0; e < 4; ++e) {
            int m = mw + i * 16 + kg * 4 + e;
            int n = tileBase + f * 16 + l15;
            float c = tanhf(acc[i][f][e] + P.bc[512 + n]);
            float u = cload(&P.u1[m * 512 + n]);
            float h = cload(&P.hs1[m * 512 + n]);
            float hn = u * h + (1.f - u) * c;
            cstore(&P.hs1[m * 512 + n], hn);
            cstore16(&P.hb1_seq[(size_t)s * SLOT + m * 512 + n], (bf16_t)hn);
          }
    }
    gbar(cnt, gen, 2 * s + 1);
  }
}

// ============================================================================
// h0 = tanh(vgg @ W_in + b_in) via bf16 MFMA, split-K=8.
// ============================================================================
__global__ __launch_bounds__(256) void h0_gemm(
    const bf16_t* __restrict__ vggb, const bf16_t* __restrict__ Wint,
    float* __restrict__ part)
{
  const int bn = blockIdx.x * 128, z = blockIdx.y, k0 = z * 512;
  const int tid = threadIdx.x;
  const int wave = tid >> 6, lane = tid & 63;
  const int wm = (wave >> 1) * 64, wn = (wave & 1) * 64;
  const int l15 = lane & 15, kg = lane >> 4;
  const bf16_t* Ap = vggb + (size_t)(wm + l15) * 4096 + k0 + kg * 8;
  const bf16_t* Bp = Wint + (size_t)(bn + wn + l15) * 4096 + k0 + kg * 8;
  f32x4 acc[4][4];
#pragma unroll
  for (int i = 0; i < 4; ++i)
#pragma unroll
    for (int j = 0; j < 4; ++j)
#pragma unroll
      for (int e = 0; e < 4; ++e) acc[i][j][e] = 0.f;
  for (int kk = 0; kk < 512; kk += 32) {
    bf16x8 a[4], b[4];
#pragma unroll
    for (int i = 0; i < 4; ++i) a[i] = *(const bf16x8*)(Ap + (size_t)i * 16 * 4096 + kk);
#pragma unroll
    for (int j = 0; j < 4; ++j) b[j] = *(const bf16x8*)(Bp + (size_t)j * 16 * 4096 + kk);
#pragma unroll
    for (int i = 0; i < 4; ++i)
#pragma unroll
      for (int j = 0; j < 4; ++j)
        acc[i][j] = __builtin_amdgcn_mfma_f32_16x16x32_bf16(a[i], b[j], acc[i][j], 0, 0, 0);
  }
#pragma unroll
  for (int fm = 0; fm < 4; ++fm)
#pragma unroll
    for (int fn = 0; fn < 4; ++fn) {
      int n = bn + wn + fn * 16 + l15;
#pragma unroll
      for (int e = 0; e < 4; ++e) {
        int m = wm + fm * 16 + kg * 4 + e;
        part[(size_t)z * SLOT + m * 512 + n] = acc[fm][fn][e];
      }
    }
}

__global__ void h0_fin(const float* __restrict__ part, const float* __restrict__ bin,
                       float* __restrict__ hs0, float* __restrict__ hs1,
                       bf16_t* __restrict__ hb00, bf16_t* __restrict__ hb10)
{
  int i = blockIdx.x * 256 + threadIdx.x;   // 65536
  int n = i & 511;
  float s = bin[n];
#pragma unroll
  for (int z = 0; z < 8; ++z) s += part[(size_t)z * SLOT + i];
  float v = tanhf(s);
  hs0[i] = v; hs1[i] = v;
  hb00[i] = (bf16_t)v; hb10[i] = (bf16_t)v;
}

__global__ void conv_bf16(const float* __restrict__ src, bf16_t* __restrict__ dst)
{
  int i = blockIdx.x * 256 + threadIdx.x;   // * 4 elems
  f4 v = ((const f4*)src)[i];
  dst[i * 4 + 0] = (bf16_t)v[0]; dst[i * 4 + 1] = (bf16_t)v[1];
  dst[i * 4 + 2] = (bf16_t)v[2]; dst[i * 4 + 3] = (bf16_t)v[3];
}

// Embedding gather -> bf16 A matrix, row m = t*128+b.
__global__ void gather_emb(const int* __restrict__ tok, const float* __restrict__ emb,
                           bf16_t* __restrict__ A)
{
  int m = blockIdx.x;
  int t = m >> 7, b = m & 127;
  int tk = tok[b * TT + t];
  const float* src = emb + (size_t)tk * 512;
  int i = threadIdx.x;
  f4 v = *(const f4*)(src + i * 4);
  bf16_t* dst = A + (size_t)m * 512 + i * 4;
  dst[0] = (bf16_t)v[0]; dst[1] = (bf16_t)v[1];
  dst[2] = (bf16_t)v[2]; dst[3] = (bf16_t)v[3];
}

// Generic transposes: dst[n*dstld + k] = src[k*512 + n]  (bf16 out)
struct TJob { const float* src; bf16_t* dst; int K; int dstld; };
struct TJobs10 { TJob j[10]; };
__global__ void transpose_gen(TJobs10 jobs)
{
  TJob jb = jobs.j[blockIdx.z];
  int k0 = blockIdx.x * 32;
  if (k0 >= jb.K) return;
  int n0 = blockIdx.y * 32;
  __shared__ float tile[32][33];
  int tx = threadIdx.x, ty = threadIdx.y;
#pragma unroll
  for (int r = 0; r < 4; ++r)
    tile[ty + 8 * r][tx] = jb.src[(size_t)(k0 + ty + 8 * r) * 512 + n0 + tx];
  __syncthreads();
#pragma unroll
  for (int r = 0; r < 4; ++r)
    jb.dst[(size_t)(n0 + ty + 8 * r) * jb.dstld + k0 + tx] = (bf16_t)tile[tx][ty + 8 * r];
}

// W_out [512,10000] -> Wto [10112,512] bf16, zero-padded rows >= 10000.
__global__ void transpose_wout(const float* __restrict__ W, bf16_t* __restrict__ dst)
{
  __shared__ float tile[32][33];
  int k0 = blockIdx.x * 32, n0 = blockIdx.y * 32;
  int tx = threadIdx.x, ty = threadIdx.y;
#pragma unroll
  for (int r = 0; r < 4; ++r) {
    int n = n0 + tx;
    tile[ty + 8 * r][tx] = (n < VV) ? W[(size_t)(k0 + ty + 8 * r) * VV + n] : 0.f;
  }
  __syncthreads();
#pragma unroll
  for (int r = 0; r < 4; ++r)
    dst[(size_t)(n0 + ty + 8 * r) * 512 + k0 + tx] = (bf16_t)tile[tx][ty + 8 * r];
}

// xbias[j][1536] = concat(b_u[j], b_r[j], b_c[j])  (only j=0 used)
__global__ void build_xbias(const float* __restrict__ bu, const float* __restrict__ br,
                            const float* __restrict__ bc, float* __restrict__ xb)
{
  int i = blockIdx.x * 256 + threadIdx.x;
  if (i < 2 * 1536) {
    int j = i / 1536, qq = i % 1536;
    int g = qq >> 9, n = qq & 511;
    const float* src = (g == 0) ? bu : (g == 1) ? br : bc;
    xb[i] = src[j * 512 + n];
  }
}

__global__ void write_hfinal(const float* __restrict__ hs0_last,
                             const float* __restrict__ hs1_last,
                             float* __restrict__ out)
{
  int i = blockIdx.x * 256 + threadIdx.x;
  out[i] = hs0_last[i];
  out[65536 + i] = hs1_last[i];
}

// ============================================================================
extern "C" void kernel_launch(void* const* d_in, const int* in_sizes, int n_in,
                              void* d_out, int out_size, void* d_ws, size_t ws_size,
                              hipStream_t stream)
{
  const int*   tok = (const int*)  d_in[0];
  const float* vgg = (const float*)d_in[1];
  const float* emb = (const float*)d_in[2];
  const float* Win = (const float*)d_in[3];
  const float* bin = (const float*)d_in[4];
  const float* Wu  = (const float*)d_in[5];
  const float* bu  = (const float*)d_in[6];
  const float* Wr  = (const float*)d_in[7];
  const float* br  = (const float*)d_in[8];
  const float* Wc  = (const float*)d_in[9];
  const float* bc  = (const float*)d_in[10];
  const float* Wo  = (const float*)d_in[11];
  const float* bo  = (const float*)d_in[12];
  float* out = (float*)d_out;

  size_t off = 0;
  auto alloc = [&](size_t bytes) -> void* {
    void* p = (char*)d_ws + off;
    off += (bytes + 255) & ~(size_t)255;
    return p;
  };
  float*  hs0   = (float*) alloc(SLOT * 4);
  float*  hs1   = (float*) alloc(SLOT * 4);
  float*  u0    = (float*) alloc(SLOT * 4);
  float*  u1    = (float*) alloc(SLOT * 4);
  bf16_t* rh0   = (bf16_t*)alloc(SLOT * 2);
  bf16_t* rh1   = (bf16_t*)alloc(SLOT * 2);
  bf16_t* hb0_seq = (bf16_t*)alloc(41 * SLOT * 2);
  bf16_t* hb1_seq = (bf16_t*)alloc(41 * SLOT * 2);
  bf16_t* Aemb  = (bf16_t*)alloc((size_t)TT * BB * 512 * 2);
  float*  xg0   = (float*) alloc((size_t)TT * BB * 1536 * 4);
  bf16_t* Btx0  = (bf16_t*)alloc((size_t)1536 * 512 * 2);
  bf16_t* Btru0 = (bf16_t*)alloc((size_t)1024 * 512 * 2);
  bf16_t* Btc0  = (bf16_t*)alloc((size_t)512 * 512 * 2);
  bf16_t* Bt1ru = (bf16_t*)alloc((size_t)1024 * 1024 * 2);
  bf16_t* Btc1  = (bf16_t*)alloc((size_t)512 * 1024 * 2);
  bf16_t* Wto   = (bf16_t*)alloc((size_t)10112 * 512 * 2);
  bf16_t* Wint  = (bf16_t*)alloc((size_t)512 * 4096 * 2);
  bf16_t* vggb  = (bf16_t*)alloc((size_t)128 * 4096 * 2);
  float*  h0part= (float*) alloc(8 * SLOT * 4);
  float*  xbias = (float*) alloc(2 * 1536 * 4);
  unsigned* syncws = (unsigned*) alloc(256);
  if (off > ws_size) return;

  // ---- prep: transposes / converts ----
  TJobs10 tj;
  tj.j[0] = { Wu,                Btx0,                512, 512 };
  tj.j[1] = { Wr,                Btx0 + 262144,       512, 512 };
  tj.j[2] = { Wc,                Btx0 + 524288,       512, 512 };
  tj.j[3] = { Wu + 262144,       Btru0,               512, 512 };
  tj.j[4] = { Wr + 262144,       Btru0 + 262144,      512, 512 };
  tj.j[5] = { Wc + 262144,       Btc0,                512, 512 };
  tj.j[6] = { Wu + 524288,       Bt1ru,               1024, 1024 };
  tj.j[7] = { Wr + 524288,       Bt1ru + 524288,      1024, 1024 };
  tj.j[8] = { Wc + 524288,       Btc1,                1024, 1024 };
  tj.j[9] = { Win,               Wint,                4096, 4096 };
  transpose_gen<<<dim3(128, 16, 10), dim3(32, 8), 0, stream>>>(tj);
  transpose_wout<<<dim3(16, 316), dim3(32, 8), 0, stream>>>(Wo, Wto);
  build_xbias<<<12, 256, 0, stream>>>(bu, br, bc, xbias);
  gather_emb<<<TT * BB, 128, 0, stream>>>(tok, emb, Aemb);
  conv_bf16<<<512, 256, 0, stream>>>(vgg, vggb);
  zero_sync<<<1, 1, 0, stream>>>(syncws);

  // ---- h0 init (bf16 MFMA, split-K) ----
  h0_gemm<<<dim3(4, 8), 256, 0, stream>>>(vggb, Wint, h0part);
  h0_fin<<<256, 256, 0, stream>>>(h0part, bin, hs0, hs1, hb0_seq, hb1_seq);

  // ---- layer-0 x-gates (batched) ----
  gemm_bt<<<dim3(40, 12), 256, 0, stream>>>(Aemb, Btx0, xbias, xg0, 1536, 1536, 0);

  // ---- persistent pipelined recurrence (fence-free barrier) ----
  PArgs pa;
  pa.Btru0 = Btru0; pa.Bt1ru = Bt1ru; pa.Btc0 = Btc0; pa.Btc1 = Btc1;
  pa.xg0 = xg0; pa.bu = bu; pa.br = br; pa.bc = bc;
  pa.hb0_seq = hb0_seq; pa.hb1_seq = hb1_seq;
  pa.rh0 = rh0; pa.rh1 = rh1;
  pa.hs0 = hs0; pa.hs1 = hs1; pa.u0 = u0; pa.u1 = u1;
  pa.sync = syncws;
  gru_persist<<<NBLK, 256, 0, stream>>>(pa);

  // ---- logits (batched, permuted to [B,T,V]) ----
  gemm_bt<<<dim3(40, 79), 256, 0, stream>>>(hb1_seq + SLOT, Wto, bo, out, VV, VV, 1);

  // ---- h_final [L,B,H] ----
  write_hfinal<<<256, 256, 0, stream>>>(hs0, hs1, out + (size_t)BB * TT * VV);
}

// Round 6
// 1994.826 us; speedup vs baseline: 1.4894x; 1.4894x over previous
//
#include <hip/hip_runtime.h>
#include <hip/hip_bf16.h>
#include <math.h>

typedef __bf16 bf16_t;
typedef __bf16 bf16x8 __attribute__((ext_vector_type(8)));
typedef float  f32x4 __attribute__((ext_vector_type(4)));
typedef float  f4    __attribute__((ext_vector_type(4)));
typedef float  f2    __attribute__((ext_vector_type(2)));
typedef unsigned short u16x4 __attribute__((ext_vector_type(4)));
typedef unsigned long long u64;

#define HS  512
#define BB  128
#define TT  40
#define VV  10000
#define VGGN 4096
#define SLOT ((size_t)65536)   // 128*512
#define NBLK 72
#define ROWP 133               // padded row-dim of LDS acc scratch

// ============================================================================
// Coherent (agent-scope, L2-bypass) accessors. ALL data written inside the
// persistent kernel is written AND read at the L3 coherence point — no plain
// cached reads of kernel-written data anywhere (stale-L2-line race surface
// from round 5 removed). Plain loads remain only for read-only inputs.
// ============================================================================
__device__ __forceinline__ u64 cld64(const void* p) {
  return __hip_atomic_load((const u64*)p, __ATOMIC_RELAXED, __HIP_MEMORY_SCOPE_AGENT);
}
__device__ __forceinline__ void cst64(void* p, u64 v) {
  __hip_atomic_store((u64*)p, v, __ATOMIC_RELAXED, __HIP_MEMORY_SCOPE_AGENT);
}
__device__ __forceinline__ f4 cload_f4(const float* p) {
  f2 lo = __builtin_bit_cast(f2, cld64(p));
  f2 hi = __builtin_bit_cast(f2, cld64(p + 2));
  return f4{lo[0], lo[1], hi[0], hi[1]};
}
__device__ __forceinline__ void cstore_f4(float* p, f4 v) {
  f2 lo = {v[0], v[1]}, hi = {v[2], v[3]};
  cst64(p,     __builtin_bit_cast(u64, lo));
  cst64(p + 2, __builtin_bit_cast(u64, hi));
}
__device__ __forceinline__ u64 pack_bf4(f4 v) {
  u16x4 r;
  r[0] = __builtin_bit_cast(unsigned short, (bf16_t)v[0]);
  r[1] = __builtin_bit_cast(unsigned short, (bf16_t)v[1]);
  r[2] = __builtin_bit_cast(unsigned short, (bf16_t)v[2]);
  r[3] = __builtin_bit_cast(unsigned short, (bf16_t)v[3]);
  return __builtin_bit_cast(u64, r);
}
__device__ __forceinline__ bf16x8 cload_bf8(const bf16_t* p) {
  f2 lo = __builtin_bit_cast(f2, cld64(p));
  f2 hi = __builtin_bit_cast(f2, cld64(p + 4));
  f4 t = {lo[0], lo[1], hi[0], hi[1]};
  return __builtin_bit_cast(bf16x8, t);
}

// ============================================================================
// Combined grid barrier over all 72 blocks — exactly the round-4-validated
// protocol (relaxed agent atomics, monotonic counter, per-launch zeroed), plus
// compiler-only memory fences so no load/store is reordered across the poll.
// __syncthreads() drains vmcnt(0) for every wave before thread0 arrives, so
// all agent stores have ACKed at L3 before the flag moves.
// ============================================================================
__device__ __forceinline__ void gbar(unsigned* cnt, unsigned* gen, unsigned idx)
{
  __syncthreads();
  asm volatile("" ::: "memory");
  if (threadIdx.x == 0) {
    unsigned a = __hip_atomic_fetch_add(cnt, 1u, __ATOMIC_RELAXED,
                                        __HIP_MEMORY_SCOPE_AGENT);
    if (a == NBLK * (idx + 1u) - 1u) {
      __hip_atomic_store(gen, idx + 1u, __ATOMIC_RELAXED,
                         __HIP_MEMORY_SCOPE_AGENT);
    } else {
      while (__hip_atomic_load(gen, __ATOMIC_RELAXED,
                               __HIP_MEMORY_SCOPE_AGENT) <= idx)
        __builtin_amdgcn_s_sleep(2);
    }
  }
  asm volatile("" ::: "memory");
  __syncthreads();
}

__global__ void zero_sync(unsigned* p) { p[0]=0u; p[1]=0u; p[2]=0u; p[3]=0u; }

// ============================================================================
// Batched MFMA GEMM: C[M,N] = A[M,512] @ Bt[N,512]^T (+bias), fp32 out.
// ============================================================================
__global__ __launch_bounds__(256) void gemm_bt(
    const bf16_t* __restrict__ A, const bf16_t* __restrict__ Bt,
    const float* __restrict__ bias, float* __restrict__ C,
    int Nvalid, int ldc, int permute_tb)
{
  const int bm = blockIdx.x * 128, bn = blockIdx.y * 128;
  const int tid = threadIdx.x;
  const int wave = tid >> 6, lane = tid & 63;
  const int wm = (wave >> 1) * 64, wn = (wave & 1) * 64;
  const int l15 = lane & 15, kg = lane >> 4;
  const bf16_t* Ap = A + (size_t)(bm + wm + l15) * 512 + kg * 8;
  const bf16_t* Bp = Bt + (size_t)(bn + wn + l15) * 512 + kg * 8;
  f32x4 acc[4][4];
#pragma unroll
  for (int i = 0; i < 4; ++i)
#pragma unroll
    for (int j = 0; j < 4; ++j)
#pragma unroll
      for (int e = 0; e < 4; ++e) acc[i][j][e] = 0.f;

  for (int kk = 0; kk < 512; kk += 32) {
    bf16x8 a[4], b[4];
#pragma unroll
    for (int i = 0; i < 4; ++i) a[i] = *(const bf16x8*)(Ap + (size_t)i * 16 * 512 + kk);
#pragma unroll
    for (int j = 0; j < 4; ++j) b[j] = *(const bf16x8*)(Bp + (size_t)j * 16 * 512 + kk);
#pragma unroll
    for (int i = 0; i < 4; ++i)
#pragma unroll
      for (int j = 0; j < 4; ++j)
        acc[i][j] = __builtin_amdgcn_mfma_f32_16x16x32_bf16(a[i], b[j], acc[i][j], 0, 0, 0);
  }

#pragma unroll
  for (int fm = 0; fm < 4; ++fm) {
#pragma unroll
    for (int fn = 0; fn < 4; ++fn) {
      int n = bn + wn + fn * 16 + l15;
      if (n >= Nvalid) continue;
      float bv = bias ? bias[n] : 0.f;
#pragma unroll
      for (int e = 0; e < 4; ++e) {
        int m = bm + wm + fm * 16 + kg * 4 + e;
        int orow = permute_tb ? ((m & 127) * TT + (m >> 7)) : m;
        C[(size_t)orow * ldc + n] = acc[fm][fn][e] + bv;
      }
    }
  }
}

// ============================================================================
// Persistent GRU recurrence. Roles as rounds 3-5:
//   [ 0,16): RU L0  64 cols of [1024,512]   K=512
//   [16,48): RU L1  32 cols of [1024,1024]  K=1024
//   [48,56): C  L0  64 cols of [512,512]    K=512
//   [56,72): C  L1  32 cols of [512,1024]   K=1024
// Stage s: phase RU ; gbar(2s) ; phase C ; gbar(2s+1).
// Epilogues: acc -> LDS transpose -> row-contiguous u64 coherent I/O.
// A-panels read coherently (kernel-written data never read via L2).
// ============================================================================
struct PArgs {
  const bf16_t *Btru0, *Bt1ru, *Btc0, *Btc1;
  const float  *xg0, *bu, *br, *bc;
  bf16_t *hb0_seq, *hb1_seq, *rh0, *rh1;
  float  *hs0, *hs1, *u0, *u1;
  unsigned *sync;   // [0]=cnt, [1]=gen
};

template<int K>
__device__ __forceinline__ void tile_gemm(
    const bf16_t* __restrict__ A0, const bf16_t* __restrict__ A1,
    const bf16_t* Bs, int wave, int lane, f32x4 (&acc)[2][4])
{
  constexpr int NF = (K == 512) ? 4 : 2;
  const int l15 = lane & 15, kg = lane >> 4;
  const int mw = wave * 32;
#pragma unroll
  for (int i = 0; i < 2; ++i)
#pragma unroll
    for (int f = 0; f < 4; ++f)
#pragma unroll
      for (int e = 0; e < 4; ++e) acc[i][f][e] = 0.f;

#pragma unroll
  for (int kk = 0; kk < K; kk += 32) {
    const bf16_t* Asrc = (kk < 512) ? A0 : A1;
    const int kc = (kk < 512 ? kk : kk - 512) + kg * 8;
    bf16x8 a[2];
#pragma unroll
    for (int i = 0; i < 2; ++i)
      a[i] = cload_bf8(Asrc + (size_t)(mw + i * 16 + l15) * 512 + kc);
    bf16x8 b[NF];
#pragma unroll
    for (int f = 0; f < NF; ++f) {
      int row = f * 16 + l15;
      int byteoff = row * (2 * K) + ((2 * kk + 16 * kg) ^ ((row & 7) << 4));
      b[f] = *(const bf16x8*)((const char*)Bs + byteoff);
    }
#pragma unroll
    for (int i = 0; i < 2; ++i)
#pragma unroll
      for (int f = 0; f < NF; ++f)
        acc[i][f] = __builtin_amdgcn_mfma_f32_16x16x32_bf16(a[i], b[f], acc[i][f], 0, 0, 0);
  }
}

// Stage acc fragments into LDS scratch: accs[col][ROWP] (col-major, padded).
template<int NF>
__device__ __forceinline__ void stage_acc(float* accs, f32x4 (&acc)[2][4],
                                          int wave, int lane)
{
  const int l15 = lane & 15, kg = lane >> 4;
  const int mw = wave * 32;
#pragma unroll
  for (int i = 0; i < 2; ++i)
#pragma unroll
    for (int f = 0; f < NF; ++f)
#pragma unroll
      for (int e = 0; e < 4; ++e)
        accs[(f * 16 + l15) * ROWP + (mw + i * 16 + kg * 4 + e)] = acc[i][f][e];
}

__global__ __launch_bounds__(256) void gru_persist(PArgs P)
{
  const int bid = blockIdx.x, tid = threadIdx.x;
  const int wave = tid >> 6, lane = tid & 63;
  unsigned* cnt = P.sync;
  unsigned* gen = P.sync + 1;

  int role, q;
  if (bid < 16)      { role = 0; q = bid; }
  else if (bid < 48) { role = 1; q = bid - 16; }
  else if (bid < 56) { role = 2; q = bid - 48; }
  else               { role = 3; q = bid - 56; }
  const int K  = (role == 0 || role == 2) ? 512 : 1024;
  const int NT = (K == 512) ? 64 : 32;
  const int tileBase = q * NT;

  const bf16_t* Wsrc =
      role == 0 ? P.Btru0 + (size_t)tileBase * 512 :
      role == 1 ? P.Bt1ru + (size_t)tileBase * 1024 :
      role == 2 ? P.Btc0  + (size_t)tileBase * 512 :
                  P.Btc1  + (size_t)tileBase * 1024;

  __shared__ bf16_t Bs[32768];          // 64 KB weight tile (swizzled)
  __shared__ float  accs[64 * ROWP];    // 34 KB epilogue transpose scratch
  {
    const int rsh = (K == 512) ? 10 : 11;
    const int rmask = 2 * K - 1;
#pragma unroll
    for (int it = 0; it < 16; ++it) {
      int ofs = (it * 256 + tid) * 16;
      int row = ofs >> rsh, cb = ofs & rmask;
      *(f4*)((char*)Bs + row * 2 * K + (cb ^ ((row & 7) << 4))) =
          *(const f4*)((const char*)Wsrc + ofs);
    }
  }
  __syncthreads();

  // epilogue mapping constants
  const int c4w = (tid & 15) * 4, r0w = tid >> 4;   // 64-col roles
  const int c4n = (tid & 7) * 4,  r0n = tid >> 3;   // 32-col roles

  for (int s = 0; s <= 40; ++s) {
    // ---------------- phase RU ----------------
    if (role == 0 && s < 40) {
      f32x4 acc[2][4];
      const bf16_t* A0 = P.hb0_seq + (size_t)s * SLOT;
      tile_gemm<512>(A0, A0, Bs, wave, lane, acc);
      stage_acc<4>(accs, acc, wave, lane);
      __syncthreads();
      const float* xg = P.xg0 + (size_t)s * 128 * 1536;
      const bool ublock = (tileBase < 512);
      const int n0 = ublock ? tileBase : tileBase - 512;
#pragma unroll
      for (int p = 0; p < 8; ++p) {
        int row = r0w + p * 16;
        f4 a;
#pragma unroll
        for (int cc = 0; cc < 4; ++cc) a[cc] = accs[(c4w + cc) * ROWP + row];
        f4 xv = *(const f4*)&xg[(size_t)row * 1536 + tileBase + c4w];
        f4 sg;
#pragma unroll
        for (int cc = 0; cc < 4; ++cc) sg[cc] = 1.f / (1.f + expf(-(a[cc] + xv[cc])));
        if (ublock) {
          cstore_f4(&P.u0[row * 512 + n0 + c4w], sg);
        } else {
          f4 h = cload_f4(&P.hs0[row * 512 + n0 + c4w]);
          cst64(&P.rh0[row * 512 + n0 + c4w], pack_bf4(sg * h));
        }
      }
    } else if (role == 1 && s >= 1) {
      f32x4 acc[2][4];
      tile_gemm<1024>(P.hb0_seq + (size_t)s * SLOT,
                      P.hb1_seq + (size_t)(s - 1) * SLOT,
                      Bs, wave, lane, acc);
      stage_acc<2>(accs, acc, wave, lane);
      __syncthreads();
      const bool ublock = (tileBase < 512);
      const int n0 = ublock ? tileBase : tileBase - 512;
      const float* bias = ublock ? (P.bu + 512 + tileBase) : (P.br + tileBase);
#pragma unroll
      for (int p = 0; p < 4; ++p) {
        int row = r0n + p * 32;
        f4 a;
#pragma unroll
        for (int cc = 0; cc < 4; ++cc) a[cc] = accs[(c4n + cc) * ROWP + row];
        f4 bv = *(const f4*)&bias[c4n];
        f4 sg;
#pragma unroll
        for (int cc = 0; cc < 4; ++cc) sg[cc] = 1.f / (1.f + expf(-(a[cc] + bv[cc])));
        if (ublock) {
          cstore_f4(&P.u1[row * 512 + n0 + c4n], sg);
        } else {
          f4 h = cload_f4(&P.hs1[row * 512 + n0 + c4n]);
          cst64(&P.rh1[row * 512 + n0 + c4n], pack_bf4(sg * h));
        }
      }
    }
    gbar(cnt, gen, 2 * s);
    // ---------------- phase C ----------------
    if (role == 2 && s < 40) {
      f32x4 acc[2][4];
      tile_gemm<512>(P.rh0, P.rh0, Bs, wave, lane, acc);
      stage_acc<4>(accs, acc, wave, lane);
      __syncthreads();
      const float* xg = P.xg0 + (size_t)s * 128 * 1536;
#pragma unroll
      for (int p = 0; p < 8; ++p) {
        int row = r0w + p * 16;
        int n = tileBase + c4w;
        f4 a;
#pragma unroll
        for (int cc = 0; cc < 4; ++cc) a[cc] = accs[(c4w + cc) * ROWP + row];
        f4 xv = *(const f4*)&xg[(size_t)row * 1536 + 1024 + n];
        f4 cg;
#pragma unroll
        for (int cc = 0; cc < 4; ++cc) cg[cc] = tanhf(a[cc] + xv[cc]);
        f4 u = cload_f4(&P.u0[row * 512 + n]);
        f4 h = cload_f4(&P.hs0[row * 512 + n]);
        f4 hn = u * h + (f4{1.f,1.f,1.f,1.f} - u) * cg;
        cstore_f4(&P.hs0[row * 512 + n], hn);
        cst64(&P.hb0_seq[(size_t)(s + 1) * SLOT + row * 512 + n], pack_bf4(hn));
      }
    } else if (role == 3 && s >= 1) {
      f32x4 acc[2][4];
      tile_gemm<1024>(P.hb0_seq + (size_t)s * SLOT, P.rh1,
                      Bs, wave, lane, acc);
      stage_acc<2>(accs, acc, wave, lane);
      __syncthreads();
#pragma unroll
      for (int p = 0; p < 4; ++p) {
        int row = r0n + p * 32;
        int n = tileBase + c4n;
        f4 a;
#pragma unroll
        for (int cc = 0; cc < 4; ++cc) a[cc] = accs[(c4n + cc) * ROWP + row];
        f4 bv = *(const f4*)&P.bc[512 + n];
        f4 cg;
#pragma unroll
        for (int cc = 0; cc < 4; ++cc) cg[cc] = tanhf(a[cc] + bv[cc]);
        f4 u = cload_f4(&P.u1[row * 512 + n]);
        f4 h = cload_f4(&P.hs1[row * 512 + n]);
        f4 hn = u * h + (f4{1.f,1.f,1.f,1.f} - u) * cg;
        cstore_f4(&P.hs1[row * 512 + n], hn);
        cst64(&P.hb1_seq[(size_t)s * SLOT + row * 512 + n], pack_bf4(hn));
      }
    }
    gbar(cnt, gen, 2 * s + 1);
  }
}

// ============================================================================
// h0 = tanh(vgg @ W_in + b_in) via bf16 MFMA, split-K=8.
// ============================================================================
__global__ __launch_bounds__(256) void h0_gemm(
    const bf16_t* __restrict__ vggb, const bf16_t* __restrict__ Wint,
    float* __restrict__ part)
{
  const int bn = blockIdx.x * 128, z = blockIdx.y, k0 = z * 512;
  const int tid = threadIdx.x;
  const int wave = tid >> 6, lane = tid & 63;
  const int wm = (wave >> 1) * 64, wn = (wave & 1) * 64;
  const int l15 = lane & 15, kg = lane >> 4;
  const bf16_t* Ap = vggb + (size_t)(wm + l15) * 4096 + k0 + kg * 8;
  const bf16_t* Bp = Wint + (size_t)(bn + wn + l15) * 4096 + k0 + kg * 8;
  f32x4 acc[4][4];
#pragma unroll
  for (int i = 0; i < 4; ++i)
#pragma unroll
    for (int j = 0; j < 4; ++j)
#pragma unroll
      for (int e = 0; e < 4; ++e) acc[i][j][e] = 0.f;
  for (int kk = 0; kk < 512; kk += 32) {
    bf16x8 a[4], b[4];
#pragma unroll
    for (int i = 0; i < 4; ++i) a[i] = *(const bf16x8*)(Ap + (size_t)i * 16 * 4096 + kk);
#pragma unroll
    for (int j = 0; j < 4; ++j) b[j] = *(const bf16x8*)(Bp + (size_t)j * 16 * 4096 + kk);
#pragma unroll
    for (int i = 0; i < 4; ++i)
#pragma unroll
      for (int j = 0; j < 4; ++j)
        acc[i][j] = __builtin_amdgcn_mfma_f32_16x16x32_bf16(a[i], b[j], acc[i][j], 0, 0, 0);
  }
#pragma unroll
  for (int fm = 0; fm < 4; ++fm)
#pragma unroll
    for (int fn = 0; fn < 4; ++fn) {
      int n = bn + wn + fn * 16 + l15;
#pragma unroll
      for (int e = 0; e < 4; ++e) {
        int m = wm + fm * 16 + kg * 4 + e;
        part[(size_t)z * SLOT + m * 512 + n] = acc[fm][fn][e];
      }
    }
}

__global__ void h0_fin(const float* __restrict__ part, const float* __restrict__ bin,
                       float* __restrict__ hs0, float* __restrict__ hs1,
                       bf16_t* __restrict__ hb00, bf16_t* __restrict__ hb10)
{
  int i = blockIdx.x * 256 + threadIdx.x;   // 65536
  int n = i & 511;
  float s = bin[n];
#pragma unroll
  for (int z = 0; z < 8; ++z) s += part[(size_t)z * SLOT + i];
  float v = tanhf(s);
  hs0[i] = v; hs1[i] = v;
  hb00[i] = (bf16_t)v; hb10[i] = (bf16_t)v;
}

__global__ void conv_bf16(const float* __restrict__ src, bf16_t* __restrict__ dst)
{
  int i = blockIdx.x * 256 + threadIdx.x;
  f4 v = ((const f4*)src)[i];
  dst[i * 4 + 0] = (bf16_t)v[0]; dst[i * 4 + 1] = (bf16_t)v[1];
  dst[i * 4 + 2] = (bf16_t)v[2]; dst[i * 4 + 3] = (bf16_t)v[3];
}

__global__ void gather_emb(const int* __restrict__ tok, const float* __restrict__ emb,
                           bf16_t* __restrict__ A)
{
  int m = blockIdx.x;
  int t = m >> 7, b = m & 127;
  int tk = tok[b * TT + t];
  const float* src = emb + (size_t)tk * 512;
  int i = threadIdx.x;
  f4 v = *(const f4*)(src + i * 4);
  bf16_t* dst = A + (size_t)m * 512 + i * 4;
  dst[0] = (bf16_t)v[0]; dst[1] = (bf16_t)v[1];
  dst[2] = (bf16_t)v[2]; dst[3] = (bf16_t)v[3];
}

struct TJob { const float* src; bf16_t* dst; int K; int dstld; };
struct TJobs10 { TJob j[10]; };
__global__ void transpose_gen(TJobs10 jobs)
{
  TJob jb = jobs.j[blockIdx.z];
  int k0 = blockIdx.x * 32;
  if (k0 >= jb.K) return;
  int n0 = blockIdx.y * 32;
  __shared__ float tile[32][33];
  int tx = threadIdx.x, ty = threadIdx.y;
#pragma unroll
  for (int r = 0; r < 4; ++r)
    tile[ty + 8 * r][tx] = jb.src[(size_t)(k0 + ty + 8 * r) * 512 + n0 + tx];
  __syncthreads();
#pragma unroll
  for (int r = 0; r < 4; ++r)
    jb.dst[(size_t)(n0 + ty + 8 * r) * jb.dstld + k0 + tx] = (bf16_t)tile[tx][ty + 8 * r];
}

__global__ void transpose_wout(const float* __restrict__ W, bf16_t* __restrict__ dst)
{
  __shared__ float tile[32][33];
  int k0 = blockIdx.x * 32, n0 = blockIdx.y * 32;
  int tx = threadIdx.x, ty = threadIdx.y;
#pragma unroll
  for (int r = 0; r < 4; ++r) {
    int n = n0 + tx;
    tile[ty + 8 * r][tx] = (n < VV) ? W[(size_t)(k0 + ty + 8 * r) * VV + n] : 0.f;
  }
  __syncthreads();
#pragma unroll
  for (int r = 0; r < 4; ++r)
    dst[(size_t)(n0 + ty + 8 * r) * 512 + k0 + tx] = (bf16_t)tile[tx][ty + 8 * r];
}

__global__ void build_xbias(const float* __restrict__ bu, const float* __restrict__ br,
                            const float* __restrict__ bc, float* __restrict__ xb)
{
  int i = blockIdx.x * 256 + threadIdx.x;
  if (i < 2 * 1536) {
    int j = i / 1536, qq = i % 1536;
    int g = qq >> 9, n = qq & 511;
    const float* src = (g == 0) ? bu : (g == 1) ? br : bc;
    xb[i] = src[j * 512 + n];
  }
}

__global__ void write_hfinal(const float* __restrict__ hs0_last,
                             const float* __restrict__ hs1_last,
                             float* __restrict__ out)
{
  int i = blockIdx.x * 256 + threadIdx.x;
  out[i] = hs0_last[i];
  out[65536 + i] = hs1_last[i];
}

// ============================================================================
extern "C" void kernel_launch(void* const* d_in, const int* in_sizes, int n_in,
                              void* d_out, int out_size, void* d_ws, size_t ws_size,
                              hipStream_t stream)
{
  const int*   tok = (const int*)  d_in[0];
  const float* vgg = (const float*)d_in[1];
  const float* emb = (const float*)d_in[2];
  const float* Win = (const float*)d_in[3];
  const float* bin = (const float*)d_in[4];
  const float* Wu  = (const float*)d_in[5];
  const float* bu  = (const float*)d_in[6];
  const float* Wr  = (const float*)d_in[7];
  const float* br  = (const float*)d_in[8];
  const float* Wc  = (const float*)d_in[9];
  const float* bc  = (const float*)d_in[10];
  const float* Wo  = (const float*)d_in[11];
  const float* bo  = (const float*)d_in[12];
  float* out = (float*)d_out;

  size_t off = 0;
  auto alloc = [&](size_t bytes) -> void* {
    void* p = (char*)d_ws + off;
    off += (bytes + 255) & ~(size_t)255;
    return p;
  };
  float*  hs0   = (float*) alloc(SLOT * 4);
  float*  hs1   = (float*) alloc(SLOT * 4);
  float*  u0    = (float*) alloc(SLOT * 4);
  float*  u1    = (float*) alloc(SLOT * 4);
  bf16_t* rh0   = (bf16_t*)alloc(SLOT * 2);
  bf16_t* rh1   = (bf16_t*)alloc(SLOT * 2);
  bf16_t* hb0_seq = (bf16_t*)alloc(41 * SLOT * 2);
  bf16_t* hb1_seq = (bf16_t*)alloc(41 * SLOT * 2);
  bf16_t* Aemb  = (bf16_t*)alloc((size_t)TT * BB * 512 * 2);
  float*  xg0   = (float*) alloc((size_t)TT * BB * 1536 * 4);
  bf16_t* Btx0  = (bf16_t*)alloc((size_t)1536 * 512 * 2);
  bf16_t* Btru0 = (bf16_t*)alloc((size_t)1024 * 512 * 2);
  bf16_t* Btc0  = (bf16_t*)alloc((size_t)512 * 512 * 2);
  bf16_t* Bt1ru = (bf16_t*)alloc((size_t)1024 * 1024 * 2);
  bf16_t* Btc1  = (bf16_t*)alloc((size_t)512 * 1024 * 2);
  bf16_t* Wto   = (bf16_t*)alloc((size_t)10112 * 512 * 2);
  bf16_t* Wint  = (bf16_t*)alloc((size_t)512 * 4096 * 2);
  bf16_t* vggb  = (bf16_t*)alloc((size_t)128 * 4096 * 2);
  float*  h0part= (float*) alloc(8 * SLOT * 4);
  float*  xbias = (float*) alloc(2 * 1536 * 4);
  unsigned* syncws = (unsigned*) alloc(256);
  if (off > ws_size) return;

  TJobs10 tj;
  tj.j[0] = { Wu,                Btx0,                512, 512 };
  tj.j[1] = { Wr,                Btx0 + 262144,       512, 512 };
  tj.j[2] = { Wc,                Btx0 + 524288,       512, 512 };
  tj.j[3] = { Wu + 262144,       Btru0,               512, 512 };
  tj.j[4] = { Wr + 262144,       Btru0 + 262144,      512, 512 };
  tj.j[5] = { Wc + 262144,       Btc0,                512, 512 };
  tj.j[6] = { Wu + 524288,       Bt1ru,               1024, 1024 };
  tj.j[7] = { Wr + 524288,       Bt1ru + 524288,      1024, 1024 };
  tj.j[8] = { Wc + 524288,       Btc1,                1024, 1024 };
  tj.j[9] = { Win,               Wint,                4096, 4096 };
  transpose_gen<<<dim3(128, 16, 10), dim3(32, 8), 0, stream>>>(tj);
  transpose_wout<<<dim3(16, 316), dim3(32, 8), 0, stream>>>(Wo, Wto);
  build_xbias<<<12, 256, 0, stream>>>(bu, br, bc, xbias);
  gather_emb<<<TT * BB, 128, 0, stream>>>(tok, emb, Aemb);
  conv_bf16<<<512, 256, 0, stream>>>(vgg, vggb);
  zero_sync<<<1, 1, 0, stream>>>(syncws);

  h0_gemm<<<dim3(4, 8), 256, 0, stream>>>(vggb, Wint, h0part);
  h0_fin<<<256, 256, 0, stream>>>(h0part, bin, hs0, hs1, hb0_seq, hb1_seq);

  gemm_bt<<<dim3(40, 12), 256, 0, stream>>>(Aemb, Btx0, xbias, xg0, 1536, 1536, 0);

  PArgs pa;
  pa.Btru0 = Btru0; pa.Bt1ru = Bt1ru; pa.Btc0 = Btc0; pa.Btc1 = Btc1;
  pa.xg0 = xg0; pa.bu = bu; pa.br = br; pa.bc = bc;
  pa.hb0_seq = hb0_seq; pa.hb1_seq = hb1_seq;
  pa.rh0 = rh0; pa.rh1 = rh1;
  pa.hs0 = hs0; pa.hs1 = hs1; pa.u0 = u0; pa.u1 = u1;
  pa.sync = syncws;
  gru_persist<<<NBLK, 256, 0, stream>>>(pa);

  gemm_bt<<<dim3(40, 79), 256, 0, stream>>>(hb1_seq + SLOT, Wto, bo, out, VV, VV, 1);

  write_hfinal<<<256, 256, 0, stream>>>(hs0, hs1, out + (size_t)BB * TT * VV);
}

// Round 8
// 1883.541 us; speedup vs baseline: 1.5774x; 1.0591x over previous
//
#include <hip/hip_runtime.h>
#include <hip/hip_bf16.h>
#include <math.h>

typedef __bf16 bf16_t;
typedef __bf16 bf16x8 __attribute__((ext_vector_type(8)));
typedef float  f32x4 __attribute__((ext_vector_type(4)));
typedef float  f4    __attribute__((ext_vector_type(4)));
typedef float  f2    __attribute__((ext_vector_type(2)));
typedef unsigned short u16x4 __attribute__((ext_vector_type(4)));
typedef unsigned long long u64;

#define HS  512
#define BB  128
#define TT  40
#define VV  10000
#define VGGN 4096
#define SLOT ((size_t)65536)   // 128*512
#define NBLK 72
#define GRPS 8                 // barrier groups
#define GSZ  9                 // blocks per group
#define ROWP 133               // padded row-dim of LDS acc scratch

// ============================================================================
// Coherent (agent-scope, L2-bypass) accessors — unchanged from round 6
// (validated across graph replays).
// ============================================================================
__device__ __forceinline__ u64 cld64(const void* p) {
  return __hip_atomic_load((const u64*)p, __ATOMIC_RELAXED, __HIP_MEMORY_SCOPE_AGENT);
}
__device__ __forceinline__ void cst64(void* p, u64 v) {
  __hip_atomic_store((u64*)p, v, __ATOMIC_RELAXED, __HIP_MEMORY_SCOPE_AGENT);
}
__device__ __forceinline__ f4 cload_f4(const float* p) {
  f2 lo = __builtin_bit_cast(f2, cld64(p));
  f2 hi = __builtin_bit_cast(f2, cld64(p + 2));
  return f4{lo[0], lo[1], hi[0], hi[1]};
}
__device__ __forceinline__ void cstore_f4(float* p, f4 v) {
  f2 lo = {v[0], v[1]}, hi = {v[2], v[3]};
  cst64(p,     __builtin_bit_cast(u64, lo));
  cst64(p + 2, __builtin_bit_cast(u64, hi));
}
__device__ __forceinline__ u64 pack_bf4(f4 v) {
  u16x4 r;
  r[0] = __builtin_bit_cast(unsigned short, (bf16_t)v[0]);
  r[1] = __builtin_bit_cast(unsigned short, (bf16_t)v[1]);
  r[2] = __builtin_bit_cast(unsigned short, (bf16_t)v[2]);
  r[3] = __builtin_bit_cast(unsigned short, (bf16_t)v[3]);
  return __builtin_bit_cast(u64, r);
}
__device__ __forceinline__ bf16x8 cload_bf8(const bf16_t* p) {
  f2 lo = __builtin_bit_cast(f2, cld64(p));
  f2 hi = __builtin_bit_cast(f2, cld64(p + 4));
  f4 t = {lo[0], lo[1], hi[0], hi[1]};
  return __builtin_bit_cast(bf16x8, t);
}

// ============================================================================
// Hierarchical line-padded grid barrier with SYMMETRIC waiting.
// Round 7's role-asymmetric waiting broke the alignment invariant of the
// counting barrier (a fast block's barrier-(k+1) arrival substituted for a
// slow block's barrier-k arrival in the modular group count). With every
// block waiting at every barrier, no block can arrive at k+1 before k is
// complete -> the (a+1)%GSZ pattern fires exactly on the group's last
// barrier-k arrival. Topology keeps round 7's contention fix:
//   grpCnt[g] @ g*64 (8 lines) ; rootCnt @ 512 ; grpGen[g] @ (9+g)*64.
// 9 arrivals/line + 8 root arrivals vs round 6's 72-on-one-line; 9 pollers
// per gen line vs 71.
// ============================================================================
__device__ __forceinline__ void gbar(unsigned* sync, unsigned idx)
{
  __syncthreads();                 // per-wave vmcnt(0) drain: stores ACKed @L3
  asm volatile("" ::: "memory");
  if (threadIdx.x == 0) {
    const int g = blockIdx.x / GSZ;
    unsigned a = __hip_atomic_fetch_add(&sync[g * 64], 1u,
                                        __ATOMIC_RELAXED, __HIP_MEMORY_SCOPE_AGENT);
    if ((a + 1u) % GSZ == 0u) {    // == GSZ*(idx+1): last group arrival @ idx
      unsigned r = __hip_atomic_fetch_add(&sync[512], 1u,
                                          __ATOMIC_RELAXED, __HIP_MEMORY_SCOPE_AGENT);
      if ((r + 1u) % GRPS == 0u) { // == GRPS*(idx+1): last group overall
        unsigned k = (r + 1u) / GRPS;   // == idx+1
#pragma unroll
        for (int j = 0; j < GRPS; ++j)
          __hip_atomic_store(&sync[(9 + j) * 64], k,
                             __ATOMIC_RELAXED, __HIP_MEMORY_SCOPE_AGENT);
      }
    }
    while (__hip_atomic_load(&sync[(9 + g) * 64],
                             __ATOMIC_RELAXED, __HIP_MEMORY_SCOPE_AGENT) <= idx)
      __builtin_amdgcn_s_sleep(8);
  }
  asm volatile("" ::: "memory");
  __syncthreads();
}

__global__ void zero_sync(unsigned* p)
{
  for (int i = threadIdx.x; i < 2048; i += 256) p[i] = 0u;
}

// ============================================================================
// Batched MFMA GEMM: C[M,N] = A[M,512] @ Bt[N,512]^T (+bias), fp32 out.
// ============================================================================
__global__ __launch_bounds__(256) void gemm_bt(
    const bf16_t* __restrict__ A, const bf16_t* __restrict__ Bt,
    const float* __restrict__ bias, float* __restrict__ C,
    int Nvalid, int ldc, int permute_tb)
{
  const int bm = blockIdx.x * 128, bn = blockIdx.y * 128;
  const int tid = threadIdx.x;
  const int wave = tid >> 6, lane = tid & 63;
  const int wm = (wave >> 1) * 64, wn = (wave & 1) * 64;
  const int l15 = lane & 15, kg = lane >> 4;
  const bf16_t* Ap = A + (size_t)(bm + wm + l15) * 512 + kg * 8;
  const bf16_t* Bp = Bt + (size_t)(bn + wn + l15) * 512 + kg * 8;
  f32x4 acc[4][4];
#pragma unroll
  for (int i = 0; i < 4; ++i)
#pragma unroll
    for (int j = 0; j < 4; ++j)
#pragma unroll
      for (int e = 0; e < 4; ++e) acc[i][j][e] = 0.f;

  for (int kk = 0; kk < 512; kk += 32) {
    bf16x8 a[4], b[4];
#pragma unroll
    for (int i = 0; i < 4; ++i) a[i] = *(const bf16x8*)(Ap + (size_t)i * 16 * 512 + kk);
#pragma unroll
    for (int j = 0; j < 4; ++j) b[j] = *(const bf16x8*)(Bp + (size_t)j * 16 * 512 + kk);
#pragma unroll
    for (int i = 0; i < 4; ++i)
#pragma unroll
      for (int j = 0; j < 4; ++j)
        acc[i][j] = __builtin_amdgcn_mfma_f32_16x16x32_bf16(a[i], b[j], acc[i][j], 0, 0, 0);
  }

#pragma unroll
  for (int fm = 0; fm < 4; ++fm) {
#pragma unroll
    for (int fn = 0; fn < 4; ++fn) {
      int n = bn + wn + fn * 16 + l15;
      if (n >= Nvalid) continue;
      float bv = bias ? bias[n] : 0.f;
#pragma unroll
      for (int e = 0; e < 4; ++e) {
        int m = bm + wm + fm * 16 + kg * 4 + e;
        int orow = permute_tb ? ((m & 127) * TT + (m >> 7)) : m;
        C[(size_t)orow * ldc + n] = acc[fm][fn][e] + bv;
      }
    }
  }
}

// ============================================================================
// Persistent GRU recurrence. Roles as rounds 3-6:
//   [ 0,16): RU L0  64 cols of [1024,512]   K=512
//   [16,48): RU L1  32 cols of [1024,1024]  K=1024
//   [48,56): C  L0  64 cols of [512,512]    K=512
//   [56,72): C  L1  32 cols of [512,1024]   K=1024
// Stage s: phase RU ; gbar(2s) ; phase C ; gbar(2s+1).  (round-6 flow)
// ============================================================================
struct PArgs {
  const bf16_t *Btru0, *Bt1ru, *Btc0, *Btc1;
  const float  *xg0, *bu, *br, *bc;
  bf16_t *hb0_seq, *hb1_seq, *rh0, *rh1;
  float  *hs0, *hs1, *u0, *u1;
  unsigned *sync;
};

template<int K>
__device__ __forceinline__ void tile_gemm(
    const bf16_t* __restrict__ A0, const bf16_t* __restrict__ A1,
    const bf16_t* Bs, int wave, int lane, f32x4 (&acc)[2][4])
{
  constexpr int NF = (K == 512) ? 4 : 2;
  const int l15 = lane & 15, kg = lane >> 4;
  const int mw = wave * 32;
#pragma unroll
  for (int i = 0; i < 2; ++i)
#pragma unroll
    for (int f = 0; f < 4; ++f)
#pragma unroll
      for (int e = 0; e < 4; ++e) acc[i][f][e] = 0.f;

#pragma unroll
  for (int kk = 0; kk < K; kk += 32) {
    const bf16_t* Asrc = (kk < 512) ? A0 : A1;
    const int kc = (kk < 512 ? kk : kk - 512) + kg * 8;
    bf16x8 a[2];
#pragma unroll
    for (int i = 0; i < 2; ++i)
      a[i] = cload_bf8(Asrc + (size_t)(mw + i * 16 + l15) * 512 + kc);
    bf16x8 b[NF];
#pragma unroll
    for (int f = 0; f < NF; ++f) {
      int row = f * 16 + l15;
      int byteoff = row * (2 * K) + ((2 * kk + 16 * kg) ^ ((row & 7) << 4));
      b[f] = *(const bf16x8*)((const char*)Bs + byteoff);
    }
#pragma unroll
    for (int i = 0; i < 2; ++i)
#pragma unroll
      for (int f = 0; f < NF; ++f)
        acc[i][f] = __builtin_amdgcn_mfma_f32_16x16x32_bf16(a[i], b[f], acc[i][f], 0, 0, 0);
  }
}

// Stage acc fragments into LDS scratch: accs[col][ROWP] (col-major, padded).
template<int NF>
__device__ __forceinline__ void stage_acc(float* accs, f32x4 (&acc)[2][4],
                                          int wave, int lane)
{
  const int l15 = lane & 15, kg = lane >> 4;
  const int mw = wave * 32;
#pragma unroll
  for (int i = 0; i < 2; ++i)
#pragma unroll
    for (int f = 0; f < NF; ++f)
#pragma unroll
      for (int e = 0; e < 4; ++e)
        accs[(f * 16 + l15) * ROWP + (mw + i * 16 + kg * 4 + e)] = acc[i][f][e];
}

__global__ __launch_bounds__(256) void gru_persist(PArgs P)
{
  const int bid = blockIdx.x, tid = threadIdx.x;
  const int wave = tid >> 6, lane = tid & 63;
  unsigned* sync = P.sync;

  int role, q;
  if (bid < 16)      { role = 0; q = bid; }
  else if (bid < 48) { role = 1; q = bid - 16; }
  else if (bid < 56) { role = 2; q = bid - 48; }
  else               { role = 3; q = bid - 56; }
  const int K  = (role == 0 || role == 2) ? 512 : 1024;
  const int NT = (K == 512) ? 64 : 32;
  const int tileBase = q * NT;

  const bf16_t* Wsrc =
      role == 0 ? P.Btru0 + (size_t)tileBase * 512 :
      role == 1 ? P.Bt1ru + (size_t)tileBase * 1024 :
      role == 2 ? P.Btc0  + (size_t)tileBase * 512 :
                  P.Btc1  + (size_t)tileBase * 1024;

  __shared__ bf16_t Bs[32768];          // 64 KB weight tile (swizzled)
  __shared__ float  accs[64 * ROWP];    // 34 KB epilogue transpose scratch
  {
    const int rsh = (K == 512) ? 10 : 11;
    const int rmask = 2 * K - 1;
#pragma unroll
    for (int it = 0; it < 16; ++it) {
      int ofs = (it * 256 + tid) * 16;
      int row = ofs >> rsh, cb = ofs & rmask;
      *(f4*)((char*)Bs + row * 2 * K + (cb ^ ((row & 7) << 4))) =
          *(const f4*)((const char*)Wsrc + ofs);
    }
  }
  __syncthreads();

  // epilogue mapping constants
  const int c4w = (tid & 15) * 4, r0w = tid >> 4;   // 64-col roles
  const int c4n = (tid & 7) * 4,  r0n = tid >> 3;   // 32-col roles

  for (int s = 0; s <= 40; ++s) {
    // ---------------- phase RU ----------------
    if (role == 0 && s < 40) {
      f32x4 acc[2][4];
      const bf16_t* A0 = P.hb0_seq + (size_t)s * SLOT;
      tile_gemm<512>(A0, A0, Bs, wave, lane, acc);
      stage_acc<4>(accs, acc, wave, lane);
      __syncthreads();
      const float* xg = P.xg0 + (size_t)s * 128 * 1536;
      const bool ublock = (tileBase < 512);
      const int n0 = ublock ? tileBase : tileBase - 512;
#pragma unroll
      for (int p = 0; p < 8; ++p) {
        int row = r0w + p * 16;
        f4 a;
#pragma unroll
        for (int cc = 0; cc < 4; ++cc) a[cc] = accs[(c4w + cc) * ROWP + row];
        f4 xv = *(const f4*)&xg[(size_t)row * 1536 + tileBase + c4w];
        f4 sg;
#pragma unroll
        for (int cc = 0; cc < 4; ++cc) sg[cc] = 1.f / (1.f + expf(-(a[cc] + xv[cc])));
        if (ublock) {
          cstore_f4(&P.u0[row * 512 + n0 + c4w], sg);
        } else {
          f4 h = cload_f4(&P.hs0[row * 512 + n0 + c4w]);
          cst64(&P.rh0[row * 512 + n0 + c4w], pack_bf4(sg * h));
        }
      }
    } else if (role == 1 && s >= 1) {
      f32x4 acc[2][4];
      tile_gemm<1024>(P.hb0_seq + (size_t)s * SLOT,
                      P.hb1_seq + (size_t)(s - 1) * SLOT,
                      Bs, wave, lane, acc);
      stage_acc<2>(accs, acc, wave, lane);
      __syncthreads();
      const bool ublock = (tileBase < 512);
      const int n0 = ublock ? tileBase : tileBase - 512;
      const float* bias = ublock ? (P.bu + 512 + tileBase) : (P.br + tileBase);
#pragma unroll
      for (int p = 0; p < 4; ++p) {
        int row = r0n + p * 32;
        f4 a;
#pragma unroll
        for (int cc = 0; cc < 4; ++cc) a[cc] = accs[(c4n + cc) * ROWP + row];
        f4 bv = *(const f4*)&bias[c4n];
        f4 sg;
#pragma unroll
        for (int cc = 0; cc < 4; ++cc) sg[cc] = 1.f / (1.f + expf(-(a[cc] + bv[cc])));
        if (ublock) {
          cstore_f4(&P.u1[row * 512 + n0 + c4n], sg);
        } else {
          f4 h = cload_f4(&P.hs1[row * 512 + n0 + c4n]);
          cst64(&P.rh1[row * 512 + n0 + c4n], pack_bf4(sg * h));
        }
      }
    }
    gbar(sync, 2 * s);
    // ---------------- phase C ----------------
    if (role == 2 && s < 40) {
      f32x4 acc[2][4];
      tile_gemm<512>(P.rh0, P.rh0, Bs, wave, lane, acc);
      stage_acc<4>(accs, acc, wave, lane);
      __syncthreads();
      const float* xg = P.xg0 + (size_t)s * 128 * 1536;
#pragma unroll
      for (int p = 0; p < 8; ++p) {
        int row = r0w + p * 16;
        int n = tileBase + c4w;
        f4 a;
#pragma unroll
        for (int cc = 0; cc < 4; ++cc) a[cc] = accs[(c4w + cc) * ROWP + row];
        f4 xv = *(const f4*)&xg[(size_t)row * 1536 + 1024 + n];
        f4 cg;
#pragma unroll
        for (int cc = 0; cc < 4; ++cc) cg[cc] = tanhf(a[cc] + xv[cc]);
        f4 u = cload_f4(&P.u0[row * 512 + n]);
        f4 h = cload_f4(&P.hs0[row * 512 + n]);
        f4 hn = u * h + (f4{1.f,1.f,1.f,1.f} - u) * cg;
        cstore_f4(&P.hs0[row * 512 + n], hn);
        cst64(&P.hb0_seq[(size_t)(s + 1) * SLOT + row * 512 + n], pack_bf4(hn));
      }
    } else if (role == 3 && s >= 1) {
      f32x4 acc[2][4];
      tile_gemm<1024>(P.hb0_seq + (size_t)s * SLOT, P.rh1,
                      Bs, wave, lane, acc);
      stage_acc<2>(accs, acc, wave, lane);
      __syncthreads();
#pragma unroll
      for (int p = 0; p < 4; ++p) {
        int row = r0n + p * 32;
        int n = tileBase + c4n;
        f4 a;
#pragma unroll
        for (int cc = 0; cc < 4; ++cc) a[cc] = accs[(c4n + cc) * ROWP + row];
        f4 bv = *(const f4*)&P.bc[512 + n];
        f4 cg;
#pragma unroll
        for (int cc = 0; cc < 4; ++cc) cg[cc] = tanhf(a[cc] + bv[cc]);
        f4 u = cload_f4(&P.u1[row * 512 + n]);
        f4 h = cload_f4(&P.hs1[row * 512 + n]);
        f4 hn = u * h + (f4{1.f,1.f,1.f,1.f} - u) * cg;
        cstore_f4(&P.hs1[row * 512 + n], hn);
        cst64(&P.hb1_seq[(size_t)s * SLOT + row * 512 + n], pack_bf4(hn));
      }
    }
    gbar(sync, 2 * s + 1);
  }
}

// ============================================================================
// h0 = tanh(vgg @ W_in + b_in) via bf16 MFMA, split-K=8.
// ============================================================================
__global__ __launch_bounds__(256) void h0_gemm(
    const bf16_t* __restrict__ vggb, const bf16_t* __restrict__ Wint,
    float* __restrict__ part)
{
  const int bn = blockIdx.x * 128, z = blockIdx.y, k0 = z * 512;
  const int tid = threadIdx.x;
  const int wave = tid >> 6, lane = tid & 63;
  const int wm = (wave >> 1) * 64, wn = (wave & 1) * 64;
  const int l15 = lane & 15, kg = lane >> 4;
  const bf16_t* Ap = vggb + (size_t)(wm + l15) * 4096 + k0 + kg * 8;
  const bf16_t* Bp = Wint + (size_t)(bn + wn + l15) * 4096 + k0 + kg * 8;
  f32x4 acc[4][4];
#pragma unroll
  for (int i = 0; i < 4; ++i)
#pragma unroll
    for (int j = 0; j < 4; ++j)
#pragma unroll
      for (int e = 0; e < 4; ++e) acc[i][j][e] = 0.f;
  for (int kk = 0; kk < 512; kk += 32) {
    bf16x8 a[4], b[4];
#pragma unroll
    for (int i = 0; i < 4; ++i) a[i] = *(const bf16x8*)(Ap + (size_t)i * 16 * 4096 + kk);
#pragma unroll
    for (int j = 0; j < 4; ++j) b[j] = *(const bf16x8*)(Bp + (size_t)j * 16 * 4096 + kk);
#pragma unroll
    for (int i = 0; i < 4; ++i)
#pragma unroll
      for (int j = 0; j < 4; ++j)
        acc[i][j] = __builtin_amdgcn_mfma_f32_16x16x32_bf16(a[i], b[j], acc[i][j], 0, 0, 0);
  }
#pragma unroll
  for (int fm = 0; fm < 4; ++fm)
#pragma unroll
    for (int fn = 0; fn < 4; ++fn) {
      int n = bn + wn + fn * 16 + l15;
#pragma unroll
      for (int e = 0; e < 4; ++e) {
        int m = wm + fm * 16 + kg * 4 + e;
        part[(size_t)z * SLOT + m * 512 + n] = acc[fm][fn][e];
      }
    }
}

__global__ void h0_fin(const float* __restrict__ part, const float* __restrict__ bin,
                       float* __restrict__ hs0, float* __restrict__ hs1,
                       bf16_t* __restrict__ hb00, bf16_t* __restrict__ hb10)
{
  int i = blockIdx.x * 256 + threadIdx.x;   // 65536
  int n = i & 511;
  float s = bin[n];
#pragma unroll
  for (int z = 0; z < 8; ++z) s += part[(size_t)z * SLOT + i];
  float v = tanhf(s);
  hs0[i] = v; hs1[i] = v;
  hb00[i] = (bf16_t)v; hb10[i] = (bf16_t)v;
}

__global__ void conv_bf16(const float* __restrict__ src, bf16_t* __restrict__ dst)
{
  int i = blockIdx.x * 256 + threadIdx.x;
  f4 v = ((const f4*)src)[i];
  dst[i * 4 + 0] = (bf16_t)v[0]; dst[i * 4 + 1] = (bf16_t)v[1];
  dst[i * 4 + 2] = (bf16_t)v[2]; dst[i * 4 + 3] = (bf16_t)v[3];
}

__global__ void gather_emb(const int* __restrict__ tok, const float* __restrict__ emb,
                           bf16_t* __restrict__ A)
{
  int m = blockIdx.x;
  int t = m >> 7, b = m & 127;
  int tk = tok[b * TT + t];
  const float* src = emb + (size_t)tk * 512;
  int i = threadIdx.x;
  f4 v = *(const f4*)(src + i * 4);
  bf16_t* dst = A + (size_t)m * 512 + i * 4;
  dst[0] = (bf16_t)v[0]; dst[1] = (bf16_t)v[1];
  dst[2] = (bf16_t)v[2]; dst[3] = (bf16_t)v[3];
}

struct TJob { const float* src; bf16_t* dst; int K; int dstld; };
struct TJobs10 { TJob j[10]; };
__global__ void transpose_gen(TJobs10 jobs)
{
  TJob jb = jobs.j[blockIdx.z];
  int k0 = blockIdx.x * 32;
  if (k0 >= jb.K) return;
  int n0 = blockIdx.y * 32;
  __shared__ float tile[32][33];
  int tx = threadIdx.x, ty = threadIdx.y;
#pragma unroll
  for (int r = 0; r < 4; ++r)
    tile[ty + 8 * r][tx] = jb.src[(size_t)(k0 + ty + 8 * r) * 512 + n0 + tx];
  __syncthreads();
#pragma unroll
  for (int r = 0; r < 4; ++r)
    jb.dst[(size_t)(n0 + ty + 8 * r) * jb.dstld + k0 + tx] = (bf16_t)tile[tx][ty + 8 * r];
}

__global__ void transpose_wout(const float* __restrict__ W, bf16_t* __restrict__ dst)
{
  __shared__ float tile[32][33];
  int k0 = blockIdx.x * 32, n0 = blockIdx.y * 32;
  int tx = threadIdx.x, ty = threadIdx.y;
#pragma unroll
  for (int r = 0; r < 4; ++r) {
    int n = n0 + tx;
    tile[ty + 8 * r][tx] = (n < VV) ? W[(size_t)(k0 + ty + 8 * r) * VV + n] : 0.f;
  }
  __syncthreads();
#pragma unroll
  for (int r = 0; r < 4; ++r)
    dst[(size_t)(n0 + ty + 8 * r) * 512 + k0 + tx] = (bf16_t)tile[tx][ty + 8 * r];
}

__global__ void build_xbias(const float* __restrict__ bu, const float* __restrict__ br,
                            const float* __restrict__ bc, float* __restrict__ xb)
{
  int i = blockIdx.x * 256 + threadIdx.x;
  if (i < 2 * 1536) {
    int j = i / 1536, qq = i % 1536;
    int g = qq >> 9, n = qq & 511;
    const float* src = (g == 0) ? bu : (g == 1) ? br : bc;
    xb[i] = src[j * 512 + n];
  }
}

__global__ void write_hfinal(const float* __restrict__ hs0_last,
                             const float* __restrict__ hs1_last,
                             float* __restrict__ out)
{
  int i = blockIdx.x * 256 + threadIdx.x;
  out[i] = hs0_last[i];
  out[65536 + i] = hs1_last[i];
}

// ============================================================================
extern "C" void kernel_launch(void* const* d_in, const int* in_sizes, int n_in,
                              void* d_out, int out_size, void* d_ws, size_t ws_size,
                              hipStream_t stream)
{
  const int*   tok = (const int*)  d_in[0];
  const float* vgg = (const float*)d_in[1];
  const float* emb = (const float*)d_in[2];
  const float* Win = (const float*)d_in[3];
  const float* bin = (const float*)d_in[4];
  const float* Wu  = (const float*)d_in[5];
  const float* bu  = (const float*)d_in[6];
  const float* Wr  = (const float*)d_in[7];
  const float* br  = (const float*)d_in[8];
  const float* Wc  = (const float*)d_in[9];
  const float* bc  = (const float*)d_in[10];
  const float* Wo  = (const float*)d_in[11];
  const float* bo  = (const float*)d_in[12];
  float* out = (float*)d_out;

  size_t off = 0;
  auto alloc = [&](size_t bytes) -> void* {
    void* p = (char*)d_ws + off;
    off += (bytes + 255) & ~(size_t)255;
    return p;
  };
  float*  hs0   = (float*) alloc(SLOT * 4);
  float*  hs1   = (float*) alloc(SLOT * 4);
  float*  u0    = (float*) alloc(SLOT * 4);
  float*  u1    = (float*) alloc(SLOT * 4);
  bf16_t* rh0   = (bf16_t*)alloc(SLOT * 2);
  bf16_t* rh1   = (bf16_t*)alloc(SLOT * 2);
  bf16_t* hb0_seq = (bf16_t*)alloc(41 * SLOT * 2);
  bf16_t* hb1_seq = (bf16_t*)alloc(41 * SLOT * 2);
  bf16_t* Aemb  = (bf16_t*)alloc((size_t)TT * BB * 512 * 2);
  float*  xg0   = (float*) alloc((size_t)TT * BB * 1536 * 4);
  bf16_t* Btx0  = (bf16_t*)alloc((size_t)1536 * 512 * 2);
  bf16_t* Btru0 = (bf16_t*)alloc((size_t)1024 * 512 * 2);
  bf16_t* Btc0  = (bf16_t*)alloc((size_t)512 * 512 * 2);
  bf16_t* Bt1ru = (bf16_t*)alloc((size_t)1024 * 1024 * 2);
  bf16_t* Btc1  = (bf16_t*)alloc((size_t)512 * 1024 * 2);
  bf16_t* Wto   = (bf16_t*)alloc((size_t)10112 * 512 * 2);
  bf16_t* Wint  = (bf16_t*)alloc((size_t)512 * 4096 * 2);
  bf16_t* vggb  = (bf16_t*)alloc((size_t)128 * 4096 * 2);
  float*  h0part= (float*) alloc(8 * SLOT * 4);
  float*  xbias = (float*) alloc(2 * 1536 * 4);
  unsigned* syncws = (unsigned*) alloc(8192);
  if (off > ws_size) return;

  TJobs10 tj;
  tj.j[0] = { Wu,                Btx0,                512, 512 };
  tj.j[1] = { Wr,                Btx0 + 262144,       512, 512 };
  tj.j[2] = { Wc,                Btx0 + 524288,       512, 512 };
  tj.j[3] = { Wu + 262144,       Btru0,               512, 512 };
  tj.j[4] = { Wr + 262144,       Btru0 + 262144,      512, 512 };
  tj.j[5] = { Wc + 262144,       Btc0,                512, 512 };
  tj.j[6] = { Wu + 524288,       Bt1ru,               1024, 1024 };
  tj.j[7] = { Wr + 524288,       Bt1ru + 524288,      1024, 1024 };
  tj.j[8] = { Wc + 524288,       Btc1,                1024, 1024 };
  tj.j[9] = { Win,               Wint,                4096, 4096 };
  transpose_gen<<<dim3(128, 16, 10), dim3(32, 8), 0, stream>>>(tj);
  transpose_wout<<<dim3(16, 316), dim3(32, 8), 0, stream>>>(Wo, Wto);
  build_xbias<<<12, 256, 0, stream>>>(bu, br, bc, xbias);
  gather_emb<<<TT * BB, 128, 0, stream>>>(tok, emb, Aemb);
  conv_bf16<<<512, 256, 0, stream>>>(vgg, vggb);
  zero_sync<<<1, 256, 0, stream>>>(syncws);

  h0_gemm<<<dim3(4, 8), 256, 0, stream>>>(vggb, Wint, h0part);
  h0_fin<<<256, 256, 0, stream>>>(h0part, bin, hs0, hs1, hb0_seq, hb1_seq);

  gemm_bt<<<dim3(40, 12), 256, 0, stream>>>(Aemb, Btx0, xbias, xg0, 1536, 1536, 0);

  PArgs pa;
  pa.Btru0 = Btru0; pa.Bt1ru = Bt1ru; pa.Btc0 = Btc0; pa.Btc1 = Btc1;
  pa.xg0 = xg0; pa.bu = bu; pa.br = br; pa.bc = bc;
  pa.hb0_seq = hb0_seq; pa.hb1_seq = hb1_seq;
  pa.rh0 = rh0; pa.rh1 = rh1;
  pa.hs0 = hs0; pa.hs1 = hs1; pa.u0 = u0; pa.u1 = u1;
  pa.sync = syncws;
  gru_persist<<<NBLK, 256, 0, stream>>>(pa);

  gemm_bt<<<dim3(40, 79), 256, 0, stream>>>(hb1_seq + SLOT, Wto, bo, out, VV, VV, 1);

  write_hfinal<<<256, 256, 0, stream>>>(hs0, hs1, out + (size_t)BB * TT * VV);
}